// Round 1
// baseline (939.677 us; speedup 1.0000x reference)
//
#include <hip/hip_runtime.h>
#include <hip/hip_bf16.h>
#include <stdint.h>

// B=16, N=4096, C=768, H=8, D=96
// Pipeline: cvt(x,wqkv,wproj) -> qkv gemm (bf16 mfma) -> q^T k + softmax -> attn@v -> proj gemm
typedef __bf16 bf16;
typedef __bf16 bf16x8 __attribute__((ext_vector_type(8)));
typedef __bf16 bf16x4 __attribute__((ext_vector_type(4)));
typedef float f32x4 __attribute__((ext_vector_type(4)));

__device__ __forceinline__ void gl_lds16(const bf16* g, bf16* l) {
  __builtin_amdgcn_global_load_lds(
      (const __attribute__((address_space(1))) void*)g,
      (__attribute__((address_space(3))) void*)l, 16, 0, 0);
}

__global__ void cvt_f32_bf16(const float* __restrict__ in, bf16* __restrict__ out, int n4) {
  int i = blockIdx.x * blockDim.x + threadIdx.x;
  if (i < n4) {
    float4 v = ((const float4*)in)[i];
    bf16x4 o;
    o[0] = (bf16)v.x; o[1] = (bf16)v.y; o[2] = (bf16)v.z; o[3] = (bf16)v.w;
    ((bf16x4*)out)[i] = o;
  }
}

// C[m,n] = sum_k A[m,k]*B[n,k] (+bias[n]); EPI=0: qkv epilogue (bf16 out, scale q cols), EPI=1: fp32 out
template<int EPI>
__global__ __launch_bounds__(256) void gemm_bt(
    const bf16* __restrict__ A, const bf16* __restrict__ B,
    const float* __restrict__ bias, void* __restrict__ Cout,
    int M, int N, int K, int nbn)
{
  __shared__ __align__(16) bf16 sA[128 * 32];
  __shared__ __align__(16) bf16 sB[128 * 32];
  int bm = blockIdx.x / nbn, bn = blockIdx.x % nbn;
  int m0 = bm * 128, n0 = bn * 128;
  int t = threadIdx.x;
  int wave = t >> 6, lane = t & 63;
  int wm = wave >> 1, wn = wave & 1;
  int l16 = lane & 15, quad = lane >> 4;

  f32x4 acc[4][4] = {};

  // staging: chunk c = wave*2+j covers rows c*16 + lane/4, k-bytes (lane%4)*16
  int rA = (wave * 2) * 16 + (lane >> 2);
  int kk = (lane & 3) * 8;
  const bf16* gA = A + (long)(m0 + rA) * K + kk;
  const bf16* gB = B + (long)(n0 + rA) * K + kk;

  for (int k0 = 0; k0 < K; k0 += 32) {
    gl_lds16(gA + k0,            &sA[(wave * 2) * 512]);
    gl_lds16(gA + 16 * K + k0,   &sA[(wave * 2 + 1) * 512]);
    gl_lds16(gB + k0,            &sB[(wave * 2) * 512]);
    gl_lds16(gB + 16 * K + k0,   &sB[(wave * 2 + 1) * 512]);
    __syncthreads();
    bf16x8 af[4], bfr[4];
#pragma unroll
    for (int mi = 0; mi < 4; mi++)
      af[mi] = *(const bf16x8*)&sA[(wm * 64 + mi * 16 + l16) * 32 + quad * 8];
#pragma unroll
    for (int ni = 0; ni < 4; ni++)
      bfr[ni] = *(const bf16x8*)&sB[(wn * 64 + ni * 16 + l16) * 32 + quad * 8];
#pragma unroll
    for (int mi = 0; mi < 4; mi++)
#pragma unroll
      for (int ni = 0; ni < 4; ni++)
        acc[mi][ni] = __builtin_amdgcn_mfma_f32_16x16x32_bf16(af[mi], bfr[ni], acc[mi][ni], 0, 0, 0);
    __syncthreads();
  }

#pragma unroll
  for (int mi = 0; mi < 4; mi++) {
    int row = m0 + wm * 64 + mi * 16 + quad * 4;
#pragma unroll
    for (int ni = 0; ni < 4; ni++) {
      int col = n0 + wn * 64 + ni * 16 + l16;
      float bv = bias[col];
#pragma unroll
      for (int r = 0; r < 4; r++) {
        float v = acc[mi][ni][r] + bv;
        if (EPI == 0) {
          if (col < 768) v *= 0.015625f;  // q * N^-0.5
          ((bf16*)Cout)[(long)(row + r) * N + col] = (bf16)v;
        } else {
          ((float*)Cout)[(long)(row + r) * N + col] = v;
        }
      }
    }
  }
}

// attn partials: part[bh][kb][d][e] = sum_{n in half kb} q[n,d] * k[n,e]
__global__ __launch_bounds__(256) void attn_qk(const bf16* __restrict__ qkv, float* __restrict__ part)
{
  __shared__ __align__(16) bf16 sQ[96 * 72];
  __shared__ __align__(16) bf16 sK[96 * 72];
  int bh = blockIdx.x >> 1, kb = blockIdx.x & 1;
  int b = bh >> 3, h = bh & 7;
  int t = threadIdx.x;
  int wave = t >> 6, lane = t & 63;
  int wm = wave >> 1, wn = wave & 1;
  int l16 = lane & 15, quad = lane >> 4;
  f32x4 acc[3][3] = {};
  const bf16* Qb = qkv + (long)b * 4096 * 2304 + h * 96;
  const bf16* Kb = Qb + 768;

  for (int it = 0; it < 32; it++) {
    int tok0 = kb * 2048 + it * 64;
    __syncthreads();
#pragma unroll
    for (int i = 0; i < 3; i++) {
      int id = i * 256 + t;
      int tl = id / 12, cc = id % 12;
      uint4 q4 = *(const uint4*)(Qb + (long)(tok0 + tl) * 2304 + cc * 8);
      uint4 k4 = *(const uint4*)(Kb + (long)(tok0 + tl) * 2304 + cc * 8);
      const bf16* qe = (const bf16*)&q4;
      const bf16* ke = (const bf16*)&k4;
#pragma unroll
      for (int j = 0; j < 8; j++) {
        sQ[(cc * 8 + j) * 72 + tl] = qe[j];
        sK[(cc * 8 + j) * 72 + tl] = ke[j];
      }
    }
    __syncthreads();
#pragma unroll
    for (int ks = 0; ks < 2; ks++) {
      bf16x8 af[3], bfr[3];
#pragma unroll
      for (int mi = 0; mi < 3; mi++)
        af[mi] = *(const bf16x8*)&sQ[(wm * 48 + mi * 16 + l16) * 72 + ks * 32 + quad * 8];
#pragma unroll
      for (int ni = 0; ni < 3; ni++)
        bfr[ni] = *(const bf16x8*)&sK[(wn * 48 + ni * 16 + l16) * 72 + ks * 32 + quad * 8];
#pragma unroll
      for (int mi = 0; mi < 3; mi++)
#pragma unroll
        for (int ni = 0; ni < 3; ni++)
          acc[mi][ni] = __builtin_amdgcn_mfma_f32_16x16x32_bf16(af[mi], bfr[ni], acc[mi][ni], 0, 0, 0);
    }
  }
  float* pout = part + (long)(bh * 2 + kb) * 9216;
#pragma unroll
  for (int mi = 0; mi < 3; mi++)
#pragma unroll
    for (int ni = 0; ni < 3; ni++) {
      int row = wm * 48 + mi * 16 + quad * 4;
      int col = wn * 48 + ni * 16 + l16;
#pragma unroll
      for (int r = 0; r < 4; r++)
        pout[(row + r) * 96 + col] = acc[mi][ni][r];
    }
}

// sum 2 partials, row softmax over e, cast bf16
__global__ __launch_bounds__(256) void softmax_attn(const float* __restrict__ part, bf16* __restrict__ attn)
{
  __shared__ float s[96 * 97];
  int bh = blockIdx.x;
  int t = threadIdx.x;
  const float* p0 = part + (long)bh * 2 * 9216;
  const float* p1 = p0 + 9216;
  for (int e = t; e < 9216; e += 256) {
    int r = e / 96, c = e % 96;
    s[r * 97 + c] = p0[e] + p1[e];
  }
  __syncthreads();
  if (t < 96) {
    float m = -1e30f;
    for (int i = 0; i < 96; i++) m = fmaxf(m, s[t * 97 + i]);
    float sum = 0.f;
    for (int i = 0; i < 96; i++) {
      float ev = __expf(s[t * 97 + i] - m);
      s[t * 97 + i] = ev;
      sum += ev;
    }
    float inv = 1.f / sum;
    bf16* ao = attn + (long)bh * 9216 + t * 96;
    for (int i = 0; i < 96; i++) ao[i] = (bf16)(s[t * 97 + i] * inv);
  }
}

// out2[tok, h*96+d] = sum_e v[tok,e] * attn[d,e]
__global__ __launch_bounds__(256) void attn_v(
    const bf16* __restrict__ qkv, const bf16* __restrict__ attn, bf16* __restrict__ out2)
{
  __shared__ __align__(16) bf16 sV[128 * 96];
  __shared__ __align__(16) bf16 sAt[96 * 96];
  int bh = blockIdx.x >> 5, tb = blockIdx.x & 31;
  int b = bh >> 3, h = bh & 7;
  int tok0 = tb * 128;
  int t = threadIdx.x;
  int wave = t >> 6, lane = t & 63;
  int wm = wave >> 1, wn = wave & 1;
  int l16 = lane & 15, quad = lane >> 4;
  f32x4 acc[4][3] = {};
  const bf16* Vb = qkv + (long)b * 4096 * 2304 + 1536 + h * 96;

#pragma unroll
  for (int j = 0; j < 6; j++) {
    int c = wave * 6 + j;
    int g = c * 64 + lane;
    int tok = g / 12, cc = g % 12;
    gl_lds16(Vb + (long)(tok0 + tok) * 2304 + cc * 8, &sV[c * 512]);
  }
  for (int c = wave; c < 18; c += 4) {
    int g = c * 64 + lane;
    int d = g / 12, cc = g % 12;
    gl_lds16(attn + (long)bh * 9216 + d * 96 + cc * 8, &sAt[c * 512]);
  }
  __syncthreads();
#pragma unroll
  for (int ks = 0; ks < 3; ks++) {
    bf16x8 af[4], bfr[3];
#pragma unroll
    for (int mi = 0; mi < 4; mi++)
      af[mi] = *(const bf16x8*)&sV[(wm * 64 + mi * 16 + l16) * 96 + ks * 32 + quad * 8];
#pragma unroll
    for (int ni = 0; ni < 3; ni++)
      bfr[ni] = *(const bf16x8*)&sAt[(wn * 48 + ni * 16 + l16) * 96 + ks * 32 + quad * 8];
#pragma unroll
    for (int mi = 0; mi < 4; mi++)
#pragma unroll
      for (int ni = 0; ni < 3; ni++)
        acc[mi][ni] = __builtin_amdgcn_mfma_f32_16x16x32_bf16(af[mi], bfr[ni], acc[mi][ni], 0, 0, 0);
  }
  bf16* ob = out2 + (long)(b * 4096 + tok0) * 768 + h * 96;
#pragma unroll
  for (int mi = 0; mi < 4; mi++)
#pragma unroll
    for (int ni = 0; ni < 3; ni++) {
      int row = wm * 64 + mi * 16 + quad * 4;
      int col = wn * 48 + ni * 16 + l16;
#pragma unroll
      for (int r = 0; r < 4; r++)
        ob[(long)(row + r) * 768 + col] = (bf16)acc[mi][ni][r];
    }
}

extern "C" void kernel_launch(void* const* d_in, const int* in_sizes, int n_in,
                              void* d_out, int out_size, void* d_ws, size_t ws_size,
                              hipStream_t stream) {
  const float* x      = (const float*)d_in[0];
  const float* w_qkv  = (const float*)d_in[1];
  const float* b_qkv  = (const float*)d_in[2];
  const float* w_proj = (const float*)d_in[3];
  const float* b_proj = (const float*)d_in[4];

  char* ws = (char*)d_ws;
  bf16*  Xb     = (bf16*)ws;                      // 100,663,296 B
  bf16*  Wqkvb  = (bf16*)(ws + 100663296);        //   3,538,944 B
  bf16*  Wprojb = (bf16*)(ws + 104202240);        //   1,179,648 B
  bf16*  qkvb   = (bf16*)(ws + 105381888);        // 301,989,888 B
  float* part   = (float*)(ws + 407371776);       //   9,437,184 B
  bf16*  attnb  = (bf16*)(ws + 416808960);        //   2,359,296 B
  bf16*  out2   = (bf16*)ws;                      // reuse X region (dead after qkv gemm)

  cvt_f32_bf16<<<(12582912 + 255) / 256, 256, 0, stream>>>(x, Xb, 12582912);
  cvt_f32_bf16<<<(442368 + 255) / 256, 256, 0, stream>>>(w_qkv, Wqkvb, 442368);
  cvt_f32_bf16<<<(147456 + 255) / 256, 256, 0, stream>>>(w_proj, Wprojb, 147456);

  // qkv = x @ w_qkv^T + b (q scaled), bf16 out [65536, 2304]
  gemm_bt<0><<<512 * 18, 256, 0, stream>>>(Xb, Wqkvb, b_qkv, qkvb, 65536, 2304, 768, 18);
  // attn partials per (b,h), split-K=2 over tokens
  attn_qk<<<256, 256, 0, stream>>>(qkvb, part);
  softmax_attn<<<128, 256, 0, stream>>>(part, attnb);
  // out2 = (attn @ v^T)^T merged heads -> [65536, 768] bf16
  attn_v<<<4096, 256, 0, stream>>>(qkvb, attnb, out2);
  // final: out2 @ w_proj^T + b -> fp32 d_out
  gemm_bt<1><<<512 * 6, 256, 0, stream>>>(out2, Wprojb, b_proj, d_out, 65536, 768, 768, 6);
}